// Round 8
// baseline (666.581 us; speedup 1.0000x reference)
//
#include <hip/hip_runtime.h>

#define NBLK(n, b) (((n) + (b) - 1) / (b))

// fp32 feature stride: 96 floats = 384 B = 24 * float4
#define FS 96
#define FS4 24
// fp16 message table: slice-major, 12 slices of 8 halves (16 B) per node.
// slice s base = s*N*8 halves. Gather block -> one slice; bid%12 pins slice s
// to XCDs {s%8,(s+4)%8} (HW round-robin bid%8), so each XCD L2 serves only
// 3 slices (2.4 MB) + csr16 (1.6 MB) -> L2/L3-resident gather.
// R7 lesson: NO nontemporal stores anywhere — they bypass L2/L3 and turned
// the gather into an HBM-random-read kernel (0.84 TB/s ceiling).
#define NSL 12

typedef _Float16 half8_t __attribute__((ext_vector_type(8)));
typedef float float8_t __attribute__((ext_vector_type(8)));

// ---------------- CSR build ----------------

__global__ void count_k(const int* __restrict__ dst, int* __restrict__ cnt, int e) {
  int i = blockIdx.x * blockDim.x + threadIdx.x;
  if (i < e) atomicAdd(&cnt[dst[i]], 1);
}

__global__ void isq_k(const int* __restrict__ cnt, float* __restrict__ isq, int n) {
  int i = blockIdx.x * blockDim.x + threadIdx.x;
  if (i < n) isq[i] = rsqrtf((float)cnt[i] + 1.0f);  // +1 self-loop
}

__global__ __launch_bounds__(256) void scan1_k(const int* __restrict__ cnt,
                                               int* __restrict__ rowptr,
                                               int* __restrict__ partials, int n) {
  __shared__ int ls[256];
  const int t = threadIdx.x;
  const int base = blockIdx.x * 1024 + t * 4;
  int v0 = 0, v1 = 0, v2 = 0, v3 = 0;
  if (base + 3 < n) {
    int4 q = *reinterpret_cast<const int4*>(cnt + base);
    v0 = q.x; v1 = q.y; v2 = q.z; v3 = q.w;
  } else {
    if (base < n) v0 = cnt[base];
    if (base + 1 < n) v1 = cnt[base + 1];
    if (base + 2 < n) v2 = cnt[base + 2];
  }
  int s = v0 + v1 + v2 + v3;
  ls[t] = s;
  __syncthreads();
  for (int off = 1; off < 256; off <<= 1) {
    int u = (t >= off) ? ls[t - off] : 0;
    __syncthreads();
    ls[t] += u;
    __syncthreads();
  }
  int p = ls[t] - s;  // block-local exclusive
  if (t == 255) partials[blockIdx.x] = ls[255];
  if (base < n) rowptr[base] = p;
  p += v0;
  if (base + 1 < n) rowptr[base + 1] = p;
  p += v1;
  if (base + 2 < n) rowptr[base + 2] = p;
  p += v2;
  if (base + 3 < n) rowptr[base + 3] = p;
}

__global__ __launch_bounds__(256) void scan2_k(const int* __restrict__ partials,
                                               int* __restrict__ offsets, int B) {
  __shared__ int ls[256];
  const int t = threadIdx.x;
  int v = (t < B) ? partials[t] : 0;
  ls[t] = v;
  __syncthreads();
  for (int off = 1; off < 256; off <<= 1) {
    int u = (t >= off) ? ls[t - off] : 0;
    __syncthreads();
    ls[t] += u;
    __syncthreads();
  }
  if (t < B) offsets[t] = ls[t] - v;
  if (t == B - 1) offsets[B] = ls[t];
}

__global__ __launch_bounds__(256) void scan3_k(int* __restrict__ rowptr,
                                               int* __restrict__ cursor,
                                               const int* __restrict__ offsets,
                                               int n, int B) {
  const int t = threadIdx.x;
  const int base = blockIdx.x * 1024 + t * 4;
  const int off = offsets[blockIdx.x];
  if (base + 3 < n) {
    int4 q = *reinterpret_cast<const int4*>(rowptr + base);
    q.x += off; q.y += off; q.z += off; q.w += off;
    *reinterpret_cast<int4*>(rowptr + base) = q;
    *reinterpret_cast<int4*>(cursor + base) = q;
  } else {
    for (int i = base; i < n; ++i) {
      int v = rowptr[i] + off;
      rowptr[i] = v;
      cursor[i] = v;
    }
  }
  if (base == 0 && blockIdx.x == 0) rowptr[n] = offsets[B];
}

__global__ void fill_k(const int* __restrict__ src, const int* __restrict__ dst,
                       int* __restrict__ cursor, unsigned short* __restrict__ csr, int e) {
  int i = blockIdx.x * blockDim.x + threadIdx.x;
  if (i >= e) return;
  int pos = atomicAdd(&cursor[dst[i]], 1);
  csr[pos] = (unsigned short)src[i];
}

// ---------------- dense transform (thread-per-row, W in LDS) ----------------
// XF: 0 = x, 1 = relu(x), 2 = relu(x)*sc+sh, 3 = relu(x*sc+sh)
// EPI: 0 = conv (write fp16 (acc*isq[row]) slice-major), 1 = fc (fp32 acc+bias)
// launch_bounds(256,2): allow up to 256 VGPR — NEVER let the allocator spill acc[]
// (R3 lesson: allocator chose 44 VGPR for 8 waves/SIMD and scratch-spilled -> 10x slow)

template <int K, int KP, int M, int MH, int INS, int OUTS, int XF, int EPI>
__global__ __launch_bounds__(256, 2) void gemm_k(
    const float* __restrict__ X, const float* __restrict__ W,
    const float* __restrict__ bias, const float* __restrict__ isq,
    const float* __restrict__ scale, const float* __restrict__ shift,
    void* __restrict__ OUT, int n) {
  __shared__ float Ws[KP * MH];
  __shared__ float Sc[(XF >= 2) ? KP : 1];
  __shared__ float Sh[(XF >= 2) ? KP : 1];
  const int ms = blockIdx.y;
  for (int idx = threadIdx.x; idx < KP * MH; idx += 256) {
    int k = idx / MH;
    int m = idx - k * MH;
    int col = ms * MH + m;
    Ws[idx] = (k < K && col < M) ? W[k * M + col] : 0.0f;
  }
  if constexpr (XF >= 2) {
    for (int k = threadIdx.x; k < KP; k += 256) {
      Sc[k] = (k < K) ? scale[k] : 0.0f;
      Sh[k] = (k < K) ? shift[k] : 0.0f;
    }
  }
  __syncthreads();
  const int row = blockIdx.x * 256 + threadIdx.x;
  const bool valid = row < n;
  const float* xp = X + (size_t)(valid ? row : 0) * INS;
  float acc[MH];
#pragma unroll
  for (int m = 0; m < MH; ++m) acc[m] = 0.0f;
  constexpr int V = ((KP % 4) == 0) ? 4 : 2;
  for (int k0 = 0; k0 < KP; k0 += V) {
    float xv[V];
    if constexpr (V == 4) {
      float4 t = *reinterpret_cast<const float4*>(xp + k0);
      xv[0] = t.x; xv[1] = t.y; xv[2] = t.z; xv[3] = t.w;
    } else {
      float2 t = *reinterpret_cast<const float2*>(xp + k0);
      xv[0] = t.x; xv[1] = t.y;
    }
#pragma unroll
    for (int j = 0; j < V; ++j) {
      float xval = xv[j];
      if constexpr (XF == 1) xval = fmaxf(xval, 0.0f);
      if constexpr (XF == 2) xval = fmaxf(xval, 0.0f) * Sc[k0 + j] + Sh[k0 + j];
      if constexpr (XF == 3) xval = fmaxf(xval * Sc[k0 + j] + Sh[k0 + j], 0.0f);
      const float* wrow = &Ws[(k0 + j) * MH];
#pragma unroll
      for (int m = 0; m < MH; ++m) acc[m] += xval * wrow[m];
    }
  }
  if (!valid) return;
  if constexpr (EPI == 0) {
    // slice-major fp16: slice sl = ms*(MH/8)+g, row entry 8 halves (16 B)
    const float s = isq[row];
    _Float16* Hh = (_Float16*)OUT;
#pragma unroll
    for (int g = 0; g < MH / 8; ++g) {
      const int sl = ms * (MH / 8) + g;
      half8_t hv;
#pragma unroll
      for (int i = 0; i < 8; ++i) hv[i] = (_Float16)(acc[g * 8 + i] * s);
      *reinterpret_cast<half8_t*>(Hh + (size_t)sl * n * 8 + (size_t)row * 8) = hv;
    }
  } else {
    float* O = (float*)OUT;
    const size_t base = (size_t)row * OUTS + ms * MH;
#pragma unroll
    for (int m = 0; m < MH; ++m) O[base + m] = acc[m] + bias[ms * MH + m];
  }
}

// ---------------- CSR gather-reduce: block per (slice, node-chunk) ----------------
// slice = bid % 12 -> pinned to XCDs {s%8,(s+4)%8}; per-XCD L2 holds its 3 slices.

__global__ __launch_bounds__(256, 6) void gather_k(
    const _Float16* __restrict__ H, const int* __restrict__ rowptr,
    const unsigned short* __restrict__ csr, const float* __restrict__ isq,
    const float* __restrict__ bias, float* __restrict__ A, int n) {
  const int bid = blockIdx.x;
  const int slice = bid % NSL;
  const int chunk = bid / NSL;
  const int d = chunk * 256 + threadIdx.x;
  if (d >= n) return;
  const half8_t* __restrict__ Hs =
      reinterpret_cast<const half8_t*>(H + (size_t)slice * n * 8);
  const int beg = rowptr[d];
  const int end = rowptr[d + 1];
  float8_t a0 = __builtin_convertvector(Hs[d], float8_t);  // self-loop (already *isq)
  float8_t a1 = {0, 0, 0, 0, 0, 0, 0, 0};
  float8_t a2 = a1, a3 = a1;
  int j = beg;
  for (; j + 4 <= end; j += 4) {
    int s0 = csr[j], s1 = csr[j + 1], s2 = csr[j + 2], s3 = csr[j + 3];
    a0 += __builtin_convertvector(Hs[s0], float8_t);
    a1 += __builtin_convertvector(Hs[s1], float8_t);
    a2 += __builtin_convertvector(Hs[s2], float8_t);
    a3 += __builtin_convertvector(Hs[s3], float8_t);
  }
  for (; j < end; ++j) a0 += __builtin_convertvector(Hs[csr[j]], float8_t);
  const float s = isq[d];
  float8_t r = ((a0 + a1) + (a2 + a3)) * s;
  const int c = slice * 8;
  float o[8];
#pragma unroll
  for (int i = 0; i < 8; ++i) o[i] = r[i] + ((c + i < 90) ? bias[c + i] : 0.0f);
  float4* Ap = reinterpret_cast<float4*>(A + (size_t)d * FS + c);
  Ap[0] = make_float4(o[0], o[1], o[2], o[3]);
  Ap[1] = make_float4(o[4], o[5], o[6], o[7]);
}

// ---------------- bn stats over an FS-strided fp32 buffer ----------------

template <int M, bool RELU>
__global__ __launch_bounds__(256) void bn_stats4_k(const float* __restrict__ X,
                                                   float* __restrict__ gsum,
                                                   float* __restrict__ gsq, int n) {
  __shared__ float ssum[FS];
  __shared__ float ssq[FS];
  for (int i = threadIdx.x; i < FS; i += 256) { ssum[i] = 0.0f; ssq[i] = 0.0f; }
  __syncthreads();
  const int t = threadIdx.x;
  const int cq = t % FS4;
  const int rl = t / FS4;
  constexpr int ROWS = 256 / FS4;  // 10
  const float4* __restrict__ Xp = reinterpret_cast<const float4*>(X);
  if (rl < ROWS) {
    float s0 = 0, s1 = 0, s2 = 0, s3 = 0, q0 = 0, q1 = 0, q2 = 0, q3 = 0;
    for (int r = blockIdx.x * ROWS + rl; r < n; r += gridDim.x * ROWS) {
      float4 v = Xp[(size_t)r * FS4 + cq];
      if (RELU) {
        v.x = fmaxf(v.x, 0.0f); v.y = fmaxf(v.y, 0.0f);
        v.z = fmaxf(v.z, 0.0f); v.w = fmaxf(v.w, 0.0f);
      }
      s0 += v.x; q0 += v.x * v.x;
      s1 += v.y; q1 += v.y * v.y;
      s2 += v.z; q2 += v.z * v.z;
      s3 += v.w; q3 += v.w * v.w;
    }
    const int c = cq * 4;
    if (c + 0 < M) { atomicAdd(&ssum[c + 0], s0); atomicAdd(&ssq[c + 0], q0); }
    if (c + 1 < M) { atomicAdd(&ssum[c + 1], s1); atomicAdd(&ssq[c + 1], q1); }
    if (c + 2 < M) { atomicAdd(&ssum[c + 2], s2); atomicAdd(&ssq[c + 2], q2); }
    if (c + 3 < M) { atomicAdd(&ssum[c + 3], s3); atomicAdd(&ssq[c + 3], q3); }
  }
  __syncthreads();
  for (int i = threadIdx.x; i < M; i += 256) {
    atomicAdd(&gsum[i], ssum[i]);
    atomicAdd(&gsq[i], ssq[i]);
  }
}

// ---------------- batchnorm finalize ----------------

template <int M>
__global__ void bn_final_k(const float* __restrict__ gsum, const float* __restrict__ gsq,
                           const float* __restrict__ g, const float* __restrict__ b,
                           float* __restrict__ scale, float* __restrict__ shift, float invn) {
  int c = threadIdx.x;
  if (c >= FS) return;
  if (c >= M) { scale[c] = 0.0f; shift[c] = 0.0f; return; }
  float mu = gsum[c] * invn;
  float var = gsq[c] * invn - mu * mu;
  float r = rsqrtf(var + 1e-5f);
  float sc = g[c] * r;
  scale[c] = sc;
  shift[c] = b[c] - mu * sc;
}

// ---------------- launch ----------------

extern "C" void kernel_launch(void* const* d_in, const int* in_sizes, int n_in,
                              void* d_out, int out_size, void* d_ws, size_t ws_size,
                              hipStream_t stream) {
  const float* x = (const float*)d_in[0];
  const int* ei = (const int*)d_in[1];
  const float* conv1_w = (const float*)d_in[2];
  const float* conv1_b = (const float*)d_in[3];
  const float* convs_w = (const float*)d_in[4];
  const float* convs_b = (const float*)d_in[5];
  const float* bn1_g = (const float*)d_in[6];
  const float* bn1_b = (const float*)d_in[7];
  const float* fc1_w = (const float*)d_in[8];
  const float* fc1_b = (const float*)d_in[9];
  const float* bn2_g = (const float*)d_in[10];
  const float* bn2_b = (const float*)d_in[11];
  const float* fc2_w = (const float*)d_in[12];
  const float* fc2_b = (const float*)d_in[13];
  const float* bn3_g = (const float*)d_in[14];
  const float* bn3_b = (const float*)d_in[15];
  const float* fc3_w = (const float*)d_in[16];
  const float* fc3_b = (const float*)d_in[17];

  const int N = in_sizes[0] / 128;
  const int E = in_sizes[1] / 2;
  const int* src = ei;
  const int* dst = ei + E;
  const int B = NBLK(N, 1024);

  // workspace layout (all chunks >=256B-aligned)
  float* ws = (float*)d_ws;
  float* isq = ws;                              // N
  int* rowptr = (int*)(ws + 50048);             // N+1
  int* cursor = rowptr + 50048;                 // N
  int* cnt = cursor + 50048;                    // N
  unsigned short* csr16 = (unsigned short*)(cnt + 50048);  // E ushorts
  int* partials = (int*)(csr16 + 800000);       // 64
  int* offsets = partials + 64;                 // 64+2
  float* stats = (float*)(offsets + 128);       // 5 * 192 (sum @ +0, sq @ +96)
  float* scale = stats + 5 * 192;               // 96
  float* shift = scale + 96;                    // 96
  float* bufH = shift + 96;                     // N*FS floats (fp16 slice view)
  float* bufA = bufH + (size_t)N * FS;          // N*FS floats
  _Float16* bufHh = (_Float16*)bufH;

  float* gs0 = stats + 0 * 192; float* gq0 = gs0 + 96;
  float* gs1 = stats + 1 * 192; float* gq1 = gs1 + 96;
  float* gs2 = stats + 2 * 192; float* gq2 = gs2 + 96;
  float* gs3 = stats + 3 * 192; float* gq3 = gs3 + 96;
  float* gs4 = stats + 4 * 192; float* gq4 = gs4 + 96;

  // ---- CSR build + norm ----
  hipMemsetAsync(cnt, 0, 50048 * sizeof(int), stream);
  hipMemsetAsync(stats, 0, 5 * 192 * sizeof(float), stream);
  count_k<<<NBLK(E, 256), 256, 0, stream>>>(dst, cnt, E);
  isq_k<<<NBLK(N, 256), 256, 0, stream>>>(cnt, isq, N);
  scan1_k<<<B, 256, 0, stream>>>(cnt, rowptr, partials, N);
  scan2_k<<<1, 256, 0, stream>>>(partials, offsets, B);
  scan3_k<<<B, 256, 0, stream>>>(rowptr, cursor, offsets, N, B);
  fill_k<<<NBLK(E, 256), 256, 0, stream>>>(src, dst, cursor, csr16, E);

  const int grows = NBLK(N, 256);
  const int ggath = NBLK(N, 256) * NSL;
  const float invn = 1.0f / (float)N;

  // ---- conv1: x[N,128] -> H(fp16 slices), gather -> A ----
  gemm_k<128, 128, 90, 48, 128, FS, 0, 0><<<dim3(grows, 2), 256, 0, stream>>>(
      x, conv1_w, nullptr, isq, nullptr, nullptr, bufHh, N);
  gather_k<<<ggath, 256, 0, stream>>>(bufHh, rowptr, csr16, isq, conv1_b, bufA, N);

  // ---- conv2 ----
  gemm_k<90, 96, 90, 48, FS, FS, 1, 0><<<dim3(grows, 2), 256, 0, stream>>>(
      bufA, convs_w, nullptr, isq, nullptr, nullptr, bufHh, N);
  gather_k<<<ggath, 256, 0, stream>>>(bufHh, rowptr, csr16, isq, convs_b, bufA, N);
  bn_stats4_k<90, true><<<512, 256, 0, stream>>>(bufA, gs0, gq0, N);
  bn_final_k<90><<<1, 128, 0, stream>>>(gs0, gq0, bn1_g, bn1_b, scale, shift, invn);

  // ---- conv3 ----
  gemm_k<90, 96, 90, 48, FS, FS, 2, 0><<<dim3(grows, 2), 256, 0, stream>>>(
      bufA, convs_w + 90 * 90, nullptr, isq, scale, shift, bufHh, N);
  gather_k<<<ggath, 256, 0, stream>>>(bufHh, rowptr, csr16, isq, convs_b + 90, bufA, N);
  bn_stats4_k<90, true><<<512, 256, 0, stream>>>(bufA, gs1, gq1, N);
  bn_final_k<90><<<1, 128, 0, stream>>>(gs1, gq1, bn1_g, bn1_b, scale, shift, invn);

  // ---- conv4 ----
  gemm_k<90, 96, 90, 48, FS, FS, 2, 0><<<dim3(grows, 2), 256, 0, stream>>>(
      bufA, convs_w + 2 * 90 * 90, nullptr, isq, scale, shift, bufHh, N);
  gather_k<<<ggath, 256, 0, stream>>>(bufHh, rowptr, csr16, isq, convs_b + 2 * 90, bufA, N);
  bn_stats4_k<90, true><<<512, 256, 0, stream>>>(bufA, gs2, gq2, N);
  bn_final_k<90><<<1, 128, 0, stream>>>(gs2, gq2, bn1_g, bn1_b, scale, shift, invn);

  // ---- fc1: relu+bn1 -> 80 (fp32 out into bufH) ----
  gemm_k<90, 96, 80, 40, FS, FS, 2, 1><<<dim3(grows, 2), 256, 0, stream>>>(
      bufA, fc1_w, fc1_b, nullptr, scale, shift, bufH, N);
  bn_stats4_k<80, false><<<512, 256, 0, stream>>>(bufH, gs3, gq3, N);
  bn_final_k<80><<<1, 128, 0, stream>>>(gs3, gq3, bn2_g, bn2_b, scale, shift, invn);

  // ---- fc2: bn2+relu -> 50 ----
  gemm_k<80, 80, 50, 25, FS, FS, 3, 1><<<dim3(grows, 2), 256, 0, stream>>>(
      bufH, fc2_w, fc2_b, nullptr, scale, shift, bufA, N);
  bn_stats4_k<50, false><<<512, 256, 0, stream>>>(bufA, gs4, gq4, N);
  bn_final_k<50><<<1, 128, 0, stream>>>(gs4, gq4, bn3_g, bn3_b, scale, shift, invn);

  // ---- fc3: bn3+relu -> 1 ----
  gemm_k<50, 52, 1, 1, FS, 1, 3, 1><<<dim3(grows, 1), 256, 0, stream>>>(
      bufA, fc3_w, fc3_b, nullptr, scale, shift, (float*)d_out, N);
}

// Round 11
// 575.294 us; speedup vs baseline: 1.1587x; 1.1587x over previous
//
#include <hip/hip_runtime.h>

#define NBLK(n, b) (((n) + (b) - 1) / (b))

// fp32 feature stride: 96 floats = 384 B = 24 * float4
#define FS 96
#define FS4 24
// fp16 message table: TWO ms-disjoint sub-tables (table ms at offset ms*N*48
// halves; row stride 48 halves = 96 B = 6 half8 slots). Two gemm blocks
// (blockIdx.y = ms) thus write fully DISJOINT memory regions — no cross-XCD
// same-line writes (R9/R10 false-sharing suspect eliminated by construction).
// Gather: one wave per node, 4 groups x 16 lanes; group g loads csr[r] directly
// (uniform address per group -> broadcast request, no shfl index machinery —
// R9/R10 divergent-shfl suspect eliminated). Slots: s<6 -> table0, 6<=s<12 ->
// table1. Cross-group reduce: canonical aligned __shfl_xor butterfly.

typedef _Float16 half8_t __attribute__((ext_vector_type(8)));
typedef float float8_t __attribute__((ext_vector_type(8)));

// ---------------- CSR build ----------------

__global__ void count_k(const int* __restrict__ dst, int* __restrict__ cnt, int e) {
  int i = blockIdx.x * blockDim.x + threadIdx.x;
  if (i < e) atomicAdd(&cnt[dst[i]], 1);
}

__global__ void isq_k(const int* __restrict__ cnt, float* __restrict__ isq, int n) {
  int i = blockIdx.x * blockDim.x + threadIdx.x;
  if (i < n) isq[i] = rsqrtf((float)cnt[i] + 1.0f);  // +1 self-loop
}

__global__ __launch_bounds__(256) void scan1_k(const int* __restrict__ cnt,
                                               int* __restrict__ rowptr,
                                               int* __restrict__ partials, int n) {
  __shared__ int ls[256];
  const int t = threadIdx.x;
  const int base = blockIdx.x * 1024 + t * 4;
  int v0 = 0, v1 = 0, v2 = 0, v3 = 0;
  if (base + 3 < n) {
    int4 q = *reinterpret_cast<const int4*>(cnt + base);
    v0 = q.x; v1 = q.y; v2 = q.z; v3 = q.w;
  } else {
    if (base < n) v0 = cnt[base];
    if (base + 1 < n) v1 = cnt[base + 1];
    if (base + 2 < n) v2 = cnt[base + 2];
  }
  int s = v0 + v1 + v2 + v3;
  ls[t] = s;
  __syncthreads();
  for (int off = 1; off < 256; off <<= 1) {
    int u = (t >= off) ? ls[t - off] : 0;
    __syncthreads();
    ls[t] += u;
    __syncthreads();
  }
  int p = ls[t] - s;  // block-local exclusive
  if (t == 255) partials[blockIdx.x] = ls[255];
  if (base < n) rowptr[base] = p;
  p += v0;
  if (base + 1 < n) rowptr[base + 1] = p;
  p += v1;
  if (base + 2 < n) rowptr[base + 2] = p;
  p += v2;
  if (base + 3 < n) rowptr[base + 3] = p;
}

__global__ __launch_bounds__(256) void scan2_k(const int* __restrict__ partials,
                                               int* __restrict__ offsets, int B) {
  __shared__ int ls[256];
  const int t = threadIdx.x;
  int v = (t < B) ? partials[t] : 0;
  ls[t] = v;
  __syncthreads();
  for (int off = 1; off < 256; off <<= 1) {
    int u = (t >= off) ? ls[t - off] : 0;
    __syncthreads();
    ls[t] += u;
    __syncthreads();
  }
  if (t < B) offsets[t] = ls[t] - v;
  if (t == B - 1) offsets[B] = ls[t];
}

__global__ __launch_bounds__(256) void scan3_k(int* __restrict__ rowptr,
                                               int* __restrict__ cursor,
                                               const int* __restrict__ offsets,
                                               int n, int B) {
  const int t = threadIdx.x;
  const int base = blockIdx.x * 1024 + t * 4;
  const int off = offsets[blockIdx.x];
  if (base + 3 < n) {
    int4 q = *reinterpret_cast<const int4*>(rowptr + base);
    q.x += off; q.y += off; q.z += off; q.w += off;
    *reinterpret_cast<int4*>(rowptr + base) = q;
    *reinterpret_cast<int4*>(cursor + base) = q;
  } else {
    for (int i = base; i < n; ++i) {
      int v = rowptr[i] + off;
      rowptr[i] = v;
      cursor[i] = v;
    }
  }
  if (base == 0 && blockIdx.x == 0) rowptr[n] = offsets[B];
}

__global__ void fill_k(const int* __restrict__ src, const int* __restrict__ dst,
                       int* __restrict__ cursor, unsigned short* __restrict__ csr, int e) {
  int i = blockIdx.x * blockDim.x + threadIdx.x;
  if (i >= e) return;
  int pos = atomicAdd(&cursor[dst[i]], 1);
  csr[pos] = (unsigned short)src[i];
}

// ---------------- dense transform (thread-per-row, W in LDS) ----------------
// XF: 0 = x, 1 = relu(x), 2 = relu(x)*sc+sh, 3 = relu(x*sc+sh)
// EPI: 0 = conv (write fp16 (acc*isq[row]) into sub-table ms), 1 = fc (fp32)
// launch_bounds(256,2): allow up to 256 VGPR — NEVER let the allocator spill acc[]
// (R3 lesson: allocator chose 44 VGPR for 8 waves/SIMD and scratch-spilled -> 10x slow)

template <int K, int KP, int M, int MH, int INS, int OUTS, int XF, int EPI>
__global__ __launch_bounds__(256, 2) void gemm_k(
    const float* __restrict__ X, const float* __restrict__ W,
    const float* __restrict__ bias, const float* __restrict__ isq,
    const float* __restrict__ scale, const float* __restrict__ shift,
    void* __restrict__ OUT, int n) {
  __shared__ float Ws[KP * MH];
  __shared__ float Sc[(XF >= 2) ? KP : 1];
  __shared__ float Sh[(XF >= 2) ? KP : 1];
  const int ms = blockIdx.y;
  for (int idx = threadIdx.x; idx < KP * MH; idx += 256) {
    int k = idx / MH;
    int m = idx - k * MH;
    int col = ms * MH + m;
    Ws[idx] = (k < K && col < M) ? W[k * M + col] : 0.0f;
  }
  if constexpr (XF >= 2) {
    for (int k = threadIdx.x; k < KP; k += 256) {
      Sc[k] = (k < K) ? scale[k] : 0.0f;
      Sh[k] = (k < K) ? shift[k] : 0.0f;
    }
  }
  __syncthreads();
  const int row = blockIdx.x * 256 + threadIdx.x;
  const bool valid = row < n;
  const float* xp = X + (size_t)(valid ? row : 0) * INS;
  float acc[MH];
#pragma unroll
  for (int m = 0; m < MH; ++m) acc[m] = 0.0f;
  constexpr int V = ((KP % 4) == 0) ? 4 : 2;
  for (int k0 = 0; k0 < KP; k0 += V) {
    float xv[V];
    if constexpr (V == 4) {
      float4 t = *reinterpret_cast<const float4*>(xp + k0);
      xv[0] = t.x; xv[1] = t.y; xv[2] = t.z; xv[3] = t.w;
    } else {
      float2 t = *reinterpret_cast<const float2*>(xp + k0);
      xv[0] = t.x; xv[1] = t.y;
    }
#pragma unroll
    for (int j = 0; j < V; ++j) {
      float xval = xv[j];
      if constexpr (XF == 1) xval = fmaxf(xval, 0.0f);
      if constexpr (XF == 2) xval = fmaxf(xval, 0.0f) * Sc[k0 + j] + Sh[k0 + j];
      if constexpr (XF == 3) xval = fmaxf(xval * Sc[k0 + j] + Sh[k0 + j], 0.0f);
      const float* wrow = &Ws[(k0 + j) * MH];
#pragma unroll
      for (int m = 0; m < MH; ++m) acc[m] += xval * wrow[m];
    }
  }
  if (!valid) return;
  if constexpr (EPI == 0) {
    // sub-table ms: base ms*n*48 halves, row stride 48 halves (96 B, disjoint per ms)
    const float s = isq[row];
    _Float16* rp = (_Float16*)OUT + (size_t)ms * n * 48 + (size_t)row * 48;
#pragma unroll
    for (int g = 0; g < MH / 8; ++g) {
      half8_t hv;
#pragma unroll
      for (int i = 0; i < 8; ++i) hv[i] = (_Float16)(acc[g * 8 + i] * s);
      *reinterpret_cast<half8_t*>(rp + g * 8) = hv;
    }
  } else {
    float* O = (float*)OUT;
    const size_t base = (size_t)row * OUTS + ms * MH;
#pragma unroll
    for (int m = 0; m < MH; ++m) O[base + m] = acc[m] + bias[ms * MH + m];
  }
}

// ---------------- CSR gather-reduce: one WAVE per destination node ----------------
// 4 groups x 16 lanes; group g handles neighbor ordinals r = beg+g, +4, ...
// csr[r] loaded directly (uniform per group -> broadcast request). Lane slot
// s<6 reads table0, 6<=s<12 table1 (each 96 B/row). Unroll x2 for MLP.
// Cross-group reduce: aligned __shfl_xor butterfly (16, 32).

__global__ __launch_bounds__(256, 6) void gather_k(
    const _Float16* __restrict__ H, const int* __restrict__ rowptr,
    const unsigned short* __restrict__ csr, const float* __restrict__ isq,
    const float* __restrict__ bias, float* __restrict__ A, int n) {
  const int wid = threadIdx.x >> 6;
  const int lane = threadIdx.x & 63;
  const int d = blockIdx.x * 4 + wid;
  if (d >= n) return;
  const int g = lane >> 4;   // group 0..3
  const int s = lane & 15;   // slot; active when s < 12
  const int beg = rowptr[d];
  const int end = rowptr[d + 1];
  const half8_t* __restrict__ Hp = reinterpret_cast<const half8_t*>(H);
  // per-lane table base: slot s<6 -> table0 slot s; s in 6..11 -> table1 slot s-6
  const int sl = (s < 6) ? s : (s - 6);
  const half8_t* __restrict__ lanebase = Hp + ((s < 6) ? 0 : (size_t)n * 6) + sl;
  float8_t acc = {0, 0, 0, 0, 0, 0, 0, 0};
  float8_t acc2 = {0, 0, 0, 0, 0, 0, 0, 0};
  if (lane < 12)  // self row (already * isq[src] from gemm)
    acc += __builtin_convertvector(lanebase[(size_t)d * 6], float8_t);
  int r = beg + g;
  for (; r + 4 < end; r += 8) {
    const int v0 = (int)csr[r];
    const int v1 = (int)csr[r + 4];
    if (s < 12) {
      acc += __builtin_convertvector(lanebase[(size_t)v0 * 6], float8_t);
      acc2 += __builtin_convertvector(lanebase[(size_t)v1 * 6], float8_t);
    }
  }
  for (; r < end; r += 4) {
    const int v = (int)csr[r];
    if (s < 12) acc += __builtin_convertvector(lanebase[(size_t)v * 6], float8_t);
  }
  acc += acc2;
  // butterfly across the 4 groups (slot-aligned: partners share s)
#pragma unroll
  for (int i = 0; i < 8; ++i) acc[i] += __shfl_xor(acc[i], 16);
#pragma unroll
  for (int i = 0; i < 8; ++i) acc[i] += __shfl_xor(acc[i], 32);
  if (lane < 12) {
    const float sc = isq[d];
    const int c = lane * 8;
    float o[8];
#pragma unroll
    for (int i = 0; i < 8; ++i)
      o[i] = acc[i] * sc + ((c + i < 90) ? bias[c + i] : 0.0f);
    float4* Ap = reinterpret_cast<float4*>(A + (size_t)d * FS + c);
    Ap[0] = make_float4(o[0], o[1], o[2], o[3]);
    Ap[1] = make_float4(o[4], o[5], o[6], o[7]);
  }
}

// ---------------- bn stats over an FS-strided fp32 buffer ----------------

template <int M, bool RELU>
__global__ __launch_bounds__(256) void bn_stats4_k(const float* __restrict__ X,
                                                   float* __restrict__ gsum,
                                                   float* __restrict__ gsq, int n) {
  __shared__ float ssum[FS];
  __shared__ float ssq[FS];
  for (int i = threadIdx.x; i < FS; i += 256) { ssum[i] = 0.0f; ssq[i] = 0.0f; }
  __syncthreads();
  const int t = threadIdx.x;
  const int cq = t % FS4;
  const int rl = t / FS4;
  constexpr int ROWS = 256 / FS4;  // 10
  const float4* __restrict__ Xp = reinterpret_cast<const float4*>(X);
  if (rl < ROWS) {
    float s0 = 0, s1 = 0, s2 = 0, s3 = 0, q0 = 0, q1 = 0, q2 = 0, q3 = 0;
    for (int r = blockIdx.x * ROWS + rl; r < n; r += gridDim.x * ROWS) {
      float4 v = Xp[(size_t)r * FS4 + cq];
      if (RELU) {
        v.x = fmaxf(v.x, 0.0f); v.y = fmaxf(v.y, 0.0f);
        v.z = fmaxf(v.z, 0.0f); v.w = fmaxf(v.w, 0.0f);
      }
      s0 += v.x; q0 += v.x * v.x;
      s1 += v.y; q1 += v.y * v.y;
      s2 += v.z; q2 += v.z * v.z;
      s3 += v.w; q3 += v.w * v.w;
    }
    const int c = cq * 4;
    if (c + 0 < M) { atomicAdd(&ssum[c + 0], s0); atomicAdd(&ssq[c + 0], q0); }
    if (c + 1 < M) { atomicAdd(&ssum[c + 1], s1); atomicAdd(&ssq[c + 1], q1); }
    if (c + 2 < M) { atomicAdd(&ssum[c + 2], s2); atomicAdd(&ssq[c + 2], q2); }
    if (c + 3 < M) { atomicAdd(&ssum[c + 3], s3); atomicAdd(&ssq[c + 3], q3); }
  }
  __syncthreads();
  for (int i = threadIdx.x; i < M; i += 256) {
    atomicAdd(&gsum[i], ssum[i]);
    atomicAdd(&gsq[i], ssq[i]);
  }
}

// ---------------- batchnorm finalize ----------------

template <int M>
__global__ void bn_final_k(const float* __restrict__ gsum, const float* __restrict__ gsq,
                           const float* __restrict__ g, const float* __restrict__ b,
                           float* __restrict__ scale, float* __restrict__ shift, float invn) {
  int c = threadIdx.x;
  if (c >= FS) return;
  if (c >= M) { scale[c] = 0.0f; shift[c] = 0.0f; return; }
  float mu = gsum[c] * invn;
  float var = gsq[c] * invn - mu * mu;
  float r = rsqrtf(var + 1e-5f);
  float sc = g[c] * r;
  scale[c] = sc;
  shift[c] = b[c] - mu * sc;
}

// ---------------- launch ----------------

extern "C" void kernel_launch(void* const* d_in, const int* in_sizes, int n_in,
                              void* d_out, int out_size, void* d_ws, size_t ws_size,
                              hipStream_t stream) {
  const float* x = (const float*)d_in[0];
  const int* ei = (const int*)d_in[1];
  const float* conv1_w = (const float*)d_in[2];
  const float* conv1_b = (const float*)d_in[3];
  const float* convs_w = (const float*)d_in[4];
  const float* convs_b = (const float*)d_in[5];
  const float* bn1_g = (const float*)d_in[6];
  const float* bn1_b = (const float*)d_in[7];
  const float* fc1_w = (const float*)d_in[8];
  const float* fc1_b = (const float*)d_in[9];
  const float* bn2_g = (const float*)d_in[10];
  const float* bn2_b = (const float*)d_in[11];
  const float* fc2_w = (const float*)d_in[12];
  const float* fc2_b = (const float*)d_in[13];
  const float* bn3_g = (const float*)d_in[14];
  const float* bn3_b = (const float*)d_in[15];
  const float* fc3_w = (const float*)d_in[16];
  const float* fc3_b = (const float*)d_in[17];

  const int N = in_sizes[0] / 128;
  const int E = in_sizes[1] / 2;
  const int* src = ei;
  const int* dst = ei + E;
  const int B = NBLK(N, 1024);

  // workspace layout (all chunks >=256B-aligned)
  float* ws = (float*)d_ws;
  float* isq = ws;                              // N
  int* rowptr = (int*)(ws + 50048);             // N+1
  int* cursor = rowptr + 50048;                 // N
  int* cnt = cursor + 50048;                    // N
  unsigned short* csr16 = (unsigned short*)(cnt + 50048);  // E ushorts
  int* partials = (int*)(csr16 + 800000);       // 64
  int* offsets = partials + 64;                 // 64+2
  float* stats = (float*)(offsets + 128);       // 5 * 192 (sum @ +0, sq @ +96)
  float* scale = stats + 5 * 192;               // 96
  float* shift = scale + 96;                    // 96
  float* bufH = shift + 96;                     // N*FS floats (2 fp16 sub-tables)
  float* bufA = bufH + (size_t)N * FS;          // N*FS floats
  _Float16* bufHh = (_Float16*)bufH;

  float* gs0 = stats + 0 * 192; float* gq0 = gs0 + 96;
  float* gs1 = stats + 1 * 192; float* gq1 = gs1 + 96;
  float* gs2 = stats + 2 * 192; float* gq2 = gs2 + 96;
  float* gs3 = stats + 3 * 192; float* gq3 = gs3 + 96;
  float* gs4 = stats + 4 * 192; float* gq4 = gs4 + 96;

  // ---- CSR build + norm ----
  hipMemsetAsync(cnt, 0, 50048 * sizeof(int), stream);
  hipMemsetAsync(stats, 0, 5 * 192 * sizeof(float), stream);
  count_k<<<NBLK(E, 256), 256, 0, stream>>>(dst, cnt, E);
  isq_k<<<NBLK(N, 256), 256, 0, stream>>>(cnt, isq, N);
  scan1_k<<<B, 256, 0, stream>>>(cnt, rowptr, partials, N);
  scan2_k<<<1, 256, 0, stream>>>(partials, offsets, B);
  scan3_k<<<B, 256, 0, stream>>>(rowptr, cursor, offsets, N, B);
  fill_k<<<NBLK(E, 256), 256, 0, stream>>>(src, dst, cursor, csr16, E);

  const int grows = NBLK(N, 256);
  const int ggath = NBLK(N, 4);
  const float invn = 1.0f / (float)N;

  // ---- conv1: x[N,128] -> H(fp16 sub-tables), gather -> A ----
  gemm_k<128, 128, 90, 48, 128, FS, 0, 0><<<dim3(grows, 2), 256, 0, stream>>>(
      x, conv1_w, nullptr, isq, nullptr, nullptr, bufHh, N);
  gather_k<<<ggath, 256, 0, stream>>>(bufHh, rowptr, csr16, isq, conv1_b, bufA, N);

  // ---- conv2 ----
  gemm_k<90, 96, 90, 48, FS, FS, 1, 0><<<dim3(grows, 2), 256, 0, stream>>>(
      bufA, convs_w, nullptr, isq, nullptr, nullptr, bufHh, N);
  gather_k<<<ggath, 256, 0, stream>>>(bufHh, rowptr, csr16, isq, convs_b, bufA, N);
  bn_stats4_k<90, true><<<512, 256, 0, stream>>>(bufA, gs0, gq0, N);
  bn_final_k<90><<<1, 128, 0, stream>>>(gs0, gq0, bn1_g, bn1_b, scale, shift, invn);

  // ---- conv3 ----
  gemm_k<90, 96, 90, 48, FS, FS, 2, 0><<<dim3(grows, 2), 256, 0, stream>>>(
      bufA, convs_w + 90 * 90, nullptr, isq, scale, shift, bufHh, N);
  gather_k<<<ggath, 256, 0, stream>>>(bufHh, rowptr, csr16, isq, convs_b + 90, bufA, N);
  bn_stats4_k<90, true><<<512, 256, 0, stream>>>(bufA, gs1, gq1, N);
  bn_final_k<90><<<1, 128, 0, stream>>>(gs1, gq1, bn1_g, bn1_b, scale, shift, invn);

  // ---- conv4 ----
  gemm_k<90, 96, 90, 48, FS, FS, 2, 0><<<dim3(grows, 2), 256, 0, stream>>>(
      bufA, convs_w + 2 * 90 * 90, nullptr, isq, scale, shift, bufHh, N);
  gather_k<<<ggath, 256, 0, stream>>>(bufHh, rowptr, csr16, isq, convs_b + 2 * 90, bufA, N);
  bn_stats4_k<90, true><<<512, 256, 0, stream>>>(bufA, gs2, gq2, N);
  bn_final_k<90><<<1, 128, 0, stream>>>(gs2, gq2, bn1_g, bn1_b, scale, shift, invn);

  // ---- fc1: relu+bn1 -> 80 (fp32 out into bufH) ----
  gemm_k<90, 96, 80, 40, FS, FS, 2, 1><<<dim3(grows, 2), 256, 0, stream>>>(
      bufA, fc1_w, fc1_b, nullptr, scale, shift, bufH, N);
  bn_stats4_k<80, false><<<512, 256, 0, stream>>>(bufH, gs3, gq3, N);
  bn_final_k<80><<<1, 128, 0, stream>>>(gs3, gq3, bn2_g, bn2_b, scale, shift, invn);

  // ---- fc2: bn2+relu -> 50 ----
  gemm_k<80, 80, 50, 25, FS, FS, 3, 1><<<dim3(grows, 2), 256, 0, stream>>>(
      bufH, fc2_w, fc2_b, nullptr, scale, shift, bufA, N);
  bn_stats4_k<50, false><<<512, 256, 0, stream>>>(bufA, gs4, gq4, N);
  bn_final_k<50><<<1, 128, 0, stream>>>(gs4, gq4, bn3_g, bn3_b, scale, shift, invn);

  // ---- fc3: bn3+relu -> 1 ----
  gemm_k<50, 52, 1, 1, FS, 1, 3, 1><<<dim3(grows, 1), 256, 0, stream>>>(
      bufA, fc3_w, fc3_b, nullptr, scale, shift, (float*)d_out, N);
}